// Round 12
// baseline (8061.834 us; speedup 1.0000x reference)
//
#include <hip/hip_runtime.h>
#include <math.h>

typedef _Float16 f16;
typedef _Float16 f16x8 __attribute__((ext_vector_type(8)));
typedef _Float16 f16x4 __attribute__((ext_vector_type(4)));
typedef _Float16 f16x2 __attribute__((ext_vector_type(2)));
typedef float f32x16 __attribute__((ext_vector_type(16)));
typedef int i32x4 __attribute__((ext_vector_type(4)));

#define B_ 32
#define T_ 1024
#define I_ 128
#define H_ 512

#define NWG 64          // 32 L0-WGs + 32 L1-WGs (one-way pipeline, R11)
#define THR 512

// ---- workspace layout (bytes) ----
// Data: write-once slots, slot k = h[t=k-1]; slot = [wg 0..31][1KB block = 32b x 16c f16].
// Trailers: per (slot, wg) 16B {epoch, ck0, ck1, 0}; epoch of slot k is k.
#define OFF_TR1   0UL                 // [1025][512] = 524,800 (reserve 525,312)
#define OFF_TR2   525312UL
#define OFF_H1S   1050624UL           // 1025*32768 = 33,587,200
#define OFF_H2S   34637824UL
#define OFF_XT    68225024UL          // f16 [1024][32][128] = 8,388,608
// total 76,613,632 B

__device__ inline f32x16 mfma32(f16x8 a, f16x8 b, f32x16 c) {
  return __builtin_amdgcn_mfma_f32_32x32x16_f16(a, b, c, 0, 0, 0);
}
__device__ inline float fast_sig(float x) { return 1.f / (1.f + __expf(-x)); }
__device__ inline float fast_tanh(float x) {
  float e = __expf(-2.f * fabsf(x));
  float t = (1.f - e) / (1.f + e);
  return x < 0.f ? -t : t;
}
__device__ inline unsigned rotl32(unsigned d, unsigned r) {
  return (d << r) | (d >> ((32u - r) & 31u));
}

// sc1 = device-coherent (MALL) ops — R2/R6/R8-proven
__device__ inline unsigned ld_sc1_u32(const unsigned* p) {
  unsigned r;
  asm volatile("global_load_dword %0, %1, off sc1\n\ts_waitcnt vmcnt(0)"
               : "=v"(r) : "v"(p) : "memory");
  return r;
}
__device__ inline void st_sc1_u32(unsigned* p, unsigned v) {
  asm volatile("global_store_dword %0, %1, off sc1" :: "v"(p), "v"(v) : "memory");
}
__device__ inline void st_sc1_b128(void* p, i32x4 v) {
  asm volatile("global_store_dwordx4 %0, %1, off sc1" :: "v"(p), "v"(v) : "memory");
}
__device__ inline i32x4 ld_sc1_b128_async(const void* p) {  // no wait; wait_vm0 before use
  i32x4 r;
  asm volatile("global_load_dwordx4 %0, %1, off sc1" : "=&v"(r) : "v"(p) : "memory");
  return r;
}
__device__ inline void wait_vm0() {
  asm volatile("s_waitcnt vmcnt(0)" ::: "memory");
  __builtin_amdgcn_sched_barrier(0);
}

// one-block verify: block = 1KB (64 lanes x 16B, chunk = lane); wave-uniform verdict.
// Checksum algebra proven end-to-end in R8 (passed correctness).
__device__ inline bool verify1(i32x4 d, i32x4 t, int lane, int epoch) {
  unsigned p0 = (unsigned)d.x ^ (unsigned)d.y ^ (unsigned)d.z ^ (unsigned)d.w;
  const unsigned base = (unsigned)(4 * lane) & 31u;
  unsigned p1 = rotl32((unsigned)d.x, base) ^ rotl32((unsigned)d.y, base + 1) ^
                rotl32((unsigned)d.z, base + 2) ^ rotl32((unsigned)d.w, base + 3);
#pragma unroll
  for (int m = 1; m < 64; m <<= 1) {
    p0 ^= (unsigned)__shfl_xor((int)p0, m, 64);
    p1 ^= (unsigned)__shfl_xor((int)p1, m, 64);
  }
  return ((unsigned)t.x == (unsigned)epoch) & ((unsigned)t.y == p0) & ((unsigned)t.z == p1);
}

// LDS XOR-swizzle (R2/R6/R10-proven)
__device__ inline int swz_h(int b, int kbyte) { return b * 1024 + (kbyte ^ ((b & 7) << 4)); }
__device__ inline int swz_x(int b, int kbyte) { return b * 256  + (kbyte ^ ((b & 7) << 4)); }

// x[b][t][i] f32 -> xT[t][b][i] f16
__global__ __launch_bounds__(256) void prep_xT(const float* __restrict__ x, f16* __restrict__ xT) {
  const int idx = blockIdx.x * 256 + threadIdx.x;
  const int n4 = B_ * T_ * I_ / 4;
  if (idx < n4) {
    const int i4 = idx * 4;
    const int i  = i4 & (I_ - 1);
    const int tt = (i4 >> 7) & (T_ - 1);
    const int b  = i4 >> 17;
    float4 v = *(const float4*)(x + i4);
    f16x4 o;
    o[0] = (f16)v.x; o[1] = (f16)v.y; o[2] = (f16)v.z; o[3] = (f16)v.w;
    *(f16x4*)(xT + ((size_t)tt * B_ + b) * I_ + i) = o;
  }
}

// Role-split persistent 2-layer LSTM (R11), drain-free trailer-checksum exchange.
__global__ __launch_bounds__(THR, 1) void lstm_persist(
    const float* __restrict__ Wih0, const float* __restrict__ Whh0,
    const float* __restrict__ bih0, const float* __restrict__ bhh0,
    const float* __restrict__ Wih1, const float* __restrict__ Whh1,
    const float* __restrict__ bih1, const float* __restrict__ bhh1,
    char* ws) {
  __shared__ i32x4 h1l4[2048];          // 32KB  h1 tile (swizzled)
  __shared__ i32x4 h2l4[2048];          // 32KB  h2 tile (L1 role)
  __shared__ i32x4 xl4[512];            // 8KB   x tile (L0 role)
  __shared__ float gbuf[2 * 32 * 68];   // gate partials [kq][32b][64c pad 68]
  __shared__ float biasl[64];
  __shared__ unsigned cks[256];         // pointwise dword scratch for trailer reduce

  const int tid  = threadIdx.x;
  const int wgid = blockIdx.x;
  const int role = wgid >> 5;           // 0 = L0, 1 = L1
  const int gid  = wgid & 31;
  const int lane = tid & 63;
  const int wv   = tid >> 6;
  const int nt   = wv & 1;
  const int kq   = (wv >> 1) & 1;
  const int bl   = lane & 31;
  const int kg   = lane >> 5;

  char* tr1 = ws + OFF_TR1;
  char* tr2 = ws + OFF_TR2;
  const char* h1base = ws + OFF_H1S;
  const char* h2base = ws + OFF_H2S;

  if (tid < 64) {
    const int g = tid >> 4, hc = tid & 15;
    const int row = g * 512 + gid * 16 + hc;
    biasl[tid] = role ? (bih1[row] + bhh1[row]) : (bih0[row] + bhh0[row]);
  }

  // ---- weight preload into VGPRs (R10/R11-identical fragments; MFMA waves only) ----
  const int n    = nt * 32 + bl;
  const int wrow = (n >> 4) * 512 + gid * 16 + (n & 15);
  f16x8 wreg[32];
  if (role == 0) {
    if (wv < 4) {
#pragma unroll
      for (int ks = 0; ks < 20; ++ks) {
        const int k = kq * 320 + ks * 16 + kg * 8;
        const float* src = (k < I_) ? (Wih0 + (size_t)wrow * I_ + k)
                                    : (Whh0 + (size_t)wrow * H_ + (k - I_));
        float4 v0 = *(const float4*)(src);
        float4 v1 = *(const float4*)(src + 4);
        f16x8 h;
        h[0] = (f16)v0.x; h[1] = (f16)v0.y; h[2] = (f16)v0.z; h[3] = (f16)v0.w;
        h[4] = (f16)v1.x; h[5] = (f16)v1.y; h[6] = (f16)v1.z; h[7] = (f16)v1.w;
        wreg[ks] = h;
      }
    }
  } else {
    if (wv < 4) {
#pragma unroll
      for (int ks = 0; ks < 32; ++ks) {
        const int k = kq * 512 + ks * 16 + kg * 8;
        const float* src = (k < H_) ? (Wih1 + (size_t)wrow * H_ + k)
                                    : (Whh1 + (size_t)wrow * H_ + (k - H_));
        float4 v0 = *(const float4*)(src);
        float4 v1 = *(const float4*)(src + 4);
        f16x8 h;
        h[0] = (f16)v0.x; h[1] = (f16)v0.y; h[2] = (f16)v0.z; h[3] = (f16)v0.w;
        h[4] = (f16)v1.x; h[5] = (f16)v1.y; h[6] = (f16)v1.z; h[7] = (f16)v1.w;
        wreg[ks] = h;
      }
    }
  }

  float cst0 = 0.f, cst1 = 0.f;
  const char* h1c = (const char*)h1l4;
  const char* h2c = (const char*)h2l4;
  const char* xc  = (const char*)xl4;

  __syncthreads();

  if (role == 0) {
    // ================= layer 0 — the critical h1 loop =================
    for (int s = 0; s < T_; ++s) {
      i32x4 xv = ((const i32x4*)(ws + OFF_XT))[(size_t)s * 512 + tid];  // prefetch

      // epoch poll: all 32 trailers of h1 slot s carry epoch s
      if (s >= 1) {
        if (tid < 64) {
          const unsigned* ep = (const unsigned*)(tr1 + (size_t)s * 512 + (lane & 31) * 16);
          for (;;) {
            unsigned v = (lane < 32) ? ld_sc1_u32(ep) : (unsigned)s;
            if (__all((int)(v == (unsigned)s))) break;
            __builtin_amdgcn_s_sleep(1);
          }
        }
        __syncthreads();
      }

      // gather + verify + stage h1 slot s (sc1 loads: retry-safe freshness)
      {
        const char* src = h1base + (size_t)s * 32768;
        const char* trs = tr1 + (size_t)s * 512;
        i32x4 d1[4], t1[4];
#pragma unroll
        for (int r = 0; r < 4; ++r) d1[r] = ld_sc1_b128_async(src + (r * 512 + tid) * 16);
        if (s >= 1) {
#pragma unroll
          for (int r = 0; r < 4; ++r) t1[r] = ld_sc1_b128_async(trs + (r * 8 + wv) * 16);
        }
        wait_vm0();
        if (s >= 1) {
          bool ok0 = verify1(d1[0], t1[0], lane, s), ok1 = verify1(d1[1], t1[1], lane, s);
          bool ok2 = verify1(d1[2], t1[2], lane, s), ok3 = verify1(d1[3], t1[3], lane, s);
          int att = 0;
          while (!(ok0 && ok1 && ok2 && ok3)) {
            if (++att > 256) break;     // visible failure, never a hang
            if (!ok0) { d1[0] = ld_sc1_b128_async(src + (0 * 512 + tid) * 16);
                        t1[0] = ld_sc1_b128_async(trs + (0 * 8 + wv) * 16); }
            if (!ok1) { d1[1] = ld_sc1_b128_async(src + (1 * 512 + tid) * 16);
                        t1[1] = ld_sc1_b128_async(trs + (1 * 8 + wv) * 16); }
            if (!ok2) { d1[2] = ld_sc1_b128_async(src + (2 * 512 + tid) * 16);
                        t1[2] = ld_sc1_b128_async(trs + (2 * 8 + wv) * 16); }
            if (!ok3) { d1[3] = ld_sc1_b128_async(src + (3 * 512 + tid) * 16);
                        t1[3] = ld_sc1_b128_async(trs + (3 * 8 + wv) * 16); }
            wait_vm0();
            if (!ok0) ok0 = verify1(d1[0], t1[0], lane, s);
            if (!ok1) ok1 = verify1(d1[1], t1[1], lane, s);
            if (!ok2) ok2 = verify1(d1[2], t1[2], lane, s);
            if (!ok3) ok3 = verify1(d1[3], t1[3], lane, s);
          }
        }
#pragma unroll
        for (int r = 0; r < 4; ++r) {
          const int u = r * 512 + tid;
          const int wgs = u >> 6, b = (u >> 1) & 31, half = u & 1;
          *(i32x4*)((char*)h1l4 + swz_h(b, wgs * 32 + half * 16)) = d1[r];
        }
      }
      *(i32x4*)((char*)xl4 + swz_x(tid >> 4, (tid & 15) * 16)) = xv;
      __syncthreads();

      // MFMA (R11 L0 body verbatim)
      if (wv < 4) {
        f32x16 acc = {};
        if (kq == 0) {
#pragma unroll
          for (int ks = 0; ks < 8; ++ks) {
            f16x8 a = *(const f16x8*)(xc + swz_x(bl, (ks * 16 + kg * 8) * 2));
            acc = mfma32(a, wreg[ks], acc);
          }
#pragma unroll
          for (int ks = 8; ks < 20; ++ks) {
            f16x8 a = *(const f16x8*)(h1c + swz_h(bl, (ks * 16 + kg * 8 - I_) * 2));
            acc = mfma32(a, wreg[ks], acc);
          }
        } else {
#pragma unroll
          for (int ks = 0; ks < 20; ++ks) {
            f16x8 a = *(const f16x8*)(h1c + swz_h(bl, (192 + ks * 16 + kg * 8) * 2));
            acc = mfma32(a, wreg[ks], acc);
          }
        }
        const int cb = nt * 32 + bl;
#pragma unroll
        for (int r = 0; r < 16; ++r) {
          const int row = (r & 3) + 8 * (r >> 2) + 4 * kg;
          gbuf[kq * 2176 + row * 68 + cb] = acc[r];
        }
      }
      __syncthreads();

      // pointwise + data store (fire-and-forget) + checksum scratch
      if (tid < 256) {
        const int rb = tid >> 3, hp = tid & 7;
        const float* gr = gbuf + rb * 68;
        float hv[2];
#pragma unroll
        for (int cc = 0; cc < 2; ++cc) {
          const int c = 2 * hp + cc;
          const float pi = gr[c]      + gr[2176 + c]      + biasl[c];
          const float pf = gr[16 + c] + gr[2176 + 16 + c] + biasl[16 + c];
          const float pg = gr[32 + c] + gr[2176 + 32 + c] + biasl[32 + c];
          const float po = gr[48 + c] + gr[2176 + 48 + c] + biasl[48 + c];
          const float ig = fast_sig(pi), fg = fast_sig(pf);
          const float gg = fast_tanh(pg), og = fast_sig(po);
          const float cprev = cc ? cst1 : cst0;
          const float cnew = fg * cprev + ig * gg;
          if (cc) cst1 = cnew; else cst0 = cnew;
          hv[cc] = og * fast_tanh(cnew);
        }
        f16x2 pk; pk[0] = (f16)hv[0]; pk[1] = (f16)hv[1];
        const unsigned dw = __builtin_bit_cast(unsigned, pk);
        st_sc1_u32((unsigned*)(h1base + (size_t)(s + 1) * 32768 +
                               (size_t)gid * 1024 + rb * 32 + hp * 4), dw);
        cks[tid] = dw;                  // dword index == tid
      }
      __syncthreads();

      // trailer: wave-0 checksum reduce + sc1 store (NO drain)
      if (wv == 0) {
        unsigned q0 = cks[lane] ^ cks[64 + lane] ^ cks[128 + lane] ^ cks[192 + lane];
        unsigned q1 = rotl32(q0, (unsigned)lane & 31u);
#pragma unroll
        for (int m = 1; m < 64; m <<= 1) {
          q0 ^= (unsigned)__shfl_xor((int)q0, m, 64);
          q1 ^= (unsigned)__shfl_xor((int)q1, m, 64);
        }
        if (lane == 0) {
          i32x4 tr; tr.x = s + 1; tr.y = (int)q0; tr.z = (int)q1; tr.w = 0;
          st_sc1_b128(tr1 + (size_t)(s + 1) * 512 + gid * 16, tr);
        }
      }
      __builtin_amdgcn_sched_barrier(0);
    }
  } else {
    // ================= layer 1 — self-paced, one step behind =================
    for (int t = 0; t < T_; ++t) {
      // epoch poll: tr1 slot t+1 (epoch t+1) AND tr2 slot t (epoch t; t=0 trivial)
      if (tid < 64) {
        const unsigned* ep1 = (const unsigned*)(tr1 + (size_t)(t + 1) * 512 + (lane & 31) * 16);
        const unsigned* ep2 = (const unsigned*)(tr2 + (size_t)t * 512 + (lane & 31) * 16);
        for (;;) {
          unsigned v, tgt;
          if (lane < 32)      { v = ld_sc1_u32(ep1); tgt = (unsigned)(t + 1); }
          else if (t >= 1)    { v = ld_sc1_u32(ep2); tgt = (unsigned)t; }
          else                { v = 0; tgt = 0; }
          if (__all((int)(v == tgt))) break;
          __builtin_amdgcn_s_sleep(1);
        }
      }
      __syncthreads();

      // gather + verify + stage h1 slot t+1 and h2 slot t
      {
        const char* s1 = h1base + (size_t)(t + 1) * 32768;
        const char* r1 = tr1 + (size_t)(t + 1) * 512;
        const char* s2 = h2base + (size_t)t * 32768;
        const char* r2 = tr2 + (size_t)t * 512;
        i32x4 d1[4], t1[4], d2[4], t2[4];
#pragma unroll
        for (int r = 0; r < 4; ++r) {
          d1[r] = ld_sc1_b128_async(s1 + (r * 512 + tid) * 16);
          d2[r] = ld_sc1_b128_async(s2 + (r * 512 + tid) * 16);
          t1[r] = ld_sc1_b128_async(r1 + (r * 8 + wv) * 16);
        }
        if (t >= 1) {
#pragma unroll
          for (int r = 0; r < 4; ++r) t2[r] = ld_sc1_b128_async(r2 + (r * 8 + wv) * 16);
        }
        wait_vm0();
        {
          bool a0 = verify1(d1[0], t1[0], lane, t + 1), a1 = verify1(d1[1], t1[1], lane, t + 1);
          bool a2 = verify1(d1[2], t1[2], lane, t + 1), a3 = verify1(d1[3], t1[3], lane, t + 1);
          bool b0 = (t < 1) || verify1(d2[0], t2[0], lane, t);
          bool b1 = (t < 1) || verify1(d2[1], t2[1], lane, t);
          bool b2 = (t < 1) || verify1(d2[2], t2[2], lane, t);
          bool b3 = (t < 1) || verify1(d2[3], t2[3], lane, t);
          int att = 0;
          while (!(a0 && a1 && a2 && a3 && b0 && b1 && b2 && b3)) {
            if (++att > 256) break;
            if (!a0) { d1[0] = ld_sc1_b128_async(s1 + (0 * 512 + tid) * 16);
                       t1[0] = ld_sc1_b128_async(r1 + (0 * 8 + wv) * 16); }
            if (!a1) { d1[1] = ld_sc1_b128_async(s1 + (1 * 512 + tid) * 16);
                       t1[1] = ld_sc1_b128_async(r1 + (1 * 8 + wv) * 16); }
            if (!a2) { d1[2] = ld_sc1_b128_async(s1 + (2 * 512 + tid) * 16);
                       t1[2] = ld_sc1_b128_async(r1 + (2 * 8 + wv) * 16); }
            if (!a3) { d1[3] = ld_sc1_b128_async(s1 + (3 * 512 + tid) * 16);
                       t1[3] = ld_sc1_b128_async(r1 + (3 * 8 + wv) * 16); }
            if (!b0) { d2[0] = ld_sc1_b128_async(s2 + (0 * 512 + tid) * 16);
                       t2[0] = ld_sc1_b128_async(r2 + (0 * 8 + wv) * 16); }
            if (!b1) { d2[1] = ld_sc1_b128_async(s2 + (1 * 512 + tid) * 16);
                       t2[1] = ld_sc1_b128_async(r2 + (1 * 8 + wv) * 16); }
            if (!b2) { d2[2] = ld_sc1_b128_async(s2 + (2 * 512 + tid) * 16);
                       t2[2] = ld_sc1_b128_async(r2 + (2 * 8 + wv) * 16); }
            if (!b3) { d2[3] = ld_sc1_b128_async(s2 + (3 * 512 + tid) * 16);
                       t2[3] = ld_sc1_b128_async(r2 + (3 * 8 + wv) * 16); }
            wait_vm0();
            if (!a0) a0 = verify1(d1[0], t1[0], lane, t + 1);
            if (!a1) a1 = verify1(d1[1], t1[1], lane, t + 1);
            if (!a2) a2 = verify1(d1[2], t1[2], lane, t + 1);
            if (!a3) a3 = verify1(d1[3], t1[3], lane, t + 1);
            if (!b0) b0 = verify1(d2[0], t2[0], lane, t);
            if (!b1) b1 = verify1(d2[1], t2[1], lane, t);
            if (!b2) b2 = verify1(d2[2], t2[2], lane, t);
            if (!b3) b3 = verify1(d2[3], t2[3], lane, t);
          }
        }
#pragma unroll
        for (int r = 0; r < 4; ++r) {
          const int u = r * 512 + tid;
          const int wgs = u >> 6, b = (u >> 1) & 31, half = u & 1;
          *(i32x4*)((char*)h1l4 + swz_h(b, wgs * 32 + half * 16)) = d1[r];
          *(i32x4*)((char*)h2l4 + swz_h(b, wgs * 32 + half * 16)) = d2[r];
        }
      }
      __syncthreads();

      // MFMA (R11 L1 body verbatim)
      if (wv < 4) {
        f32x16 acc = {};
        if (kq == 0) {
#pragma unroll
          for (int ks = 0; ks < 32; ++ks) {
            f16x8 a = *(const f16x8*)(h1c + swz_h(bl, (ks * 16 + kg * 8) * 2));
            acc = mfma32(a, wreg[ks], acc);
          }
        } else {
#pragma unroll
          for (int ks = 0; ks < 32; ++ks) {
            f16x8 a = *(const f16x8*)(h2c + swz_h(bl, (ks * 16 + kg * 8) * 2));
            acc = mfma32(a, wreg[ks], acc);
          }
        }
        const int cb = nt * 32 + bl;
#pragma unroll
        for (int r = 0; r < 16; ++r) {
          const int row = (r & 3) + 8 * (r >> 2) + 4 * kg;
          gbuf[kq * 2176 + row * 68 + cb] = acc[r];
        }
      }
      __syncthreads();

      // pointwise + h2 store + checksum scratch
      if (tid < 256) {
        const int rb = tid >> 3, hp = tid & 7;
        const float* gr = gbuf + rb * 68;
        float hv[2];
#pragma unroll
        for (int cc = 0; cc < 2; ++cc) {
          const int c = 2 * hp + cc;
          const float pi = gr[c]      + gr[2176 + c]      + biasl[c];
          const float pf = gr[16 + c] + gr[2176 + 16 + c] + biasl[16 + c];
          const float pg = gr[32 + c] + gr[2176 + 32 + c] + biasl[32 + c];
          const float po = gr[48 + c] + gr[2176 + 48 + c] + biasl[48 + c];
          const float ig = fast_sig(pi), fg = fast_sig(pf);
          const float gg = fast_tanh(pg), og = fast_sig(po);
          const float cprev = cc ? cst1 : cst0;
          const float cnew = fg * cprev + ig * gg;
          if (cc) cst1 = cnew; else cst0 = cnew;
          hv[cc] = og * fast_tanh(cnew);
        }
        f16x2 pk; pk[0] = (f16)hv[0]; pk[1] = (f16)hv[1];
        const unsigned dw = __builtin_bit_cast(unsigned, pk);
        st_sc1_u32((unsigned*)(h2base + (size_t)(t + 1) * 32768 +
                               (size_t)gid * 1024 + rb * 32 + hp * 4), dw);
        cks[tid] = dw;
      }
      __syncthreads();

      // trailer for h2 slot t+1 (NO drain)
      if (wv == 0) {
        unsigned q0 = cks[lane] ^ cks[64 + lane] ^ cks[128 + lane] ^ cks[192 + lane];
        unsigned q1 = rotl32(q0, (unsigned)lane & 31u);
#pragma unroll
        for (int m = 1; m < 64; m <<= 1) {
          q0 ^= (unsigned)__shfl_xor((int)q0, m, 64);
          q1 ^= (unsigned)__shfl_xor((int)q1, m, 64);
        }
        if (lane == 0) {
          i32x4 tr; tr.x = t + 1; tr.y = (int)q0; tr.z = (int)q1; tr.w = 0;
          st_sc1_b128(tr2 + (size_t)(t + 1) * 512 + gid * 16, tr);
        }
      }
      __builtin_amdgcn_sched_barrier(0);
    }
  }
}

// fused FC1+FC2 reading block layout (R6-identical): rows bt = b*1024 + t.
__global__ __launch_bounds__(256) void fc_fused(const char* __restrict__ ws_h2,
                                                const float* __restrict__ fcW,
                                                const float* __restrict__ fcb,
                                                const float* __restrict__ fc2W,
                                                const float* __restrict__ fc2b,
                                                float* __restrict__ out) {
  __shared__ float hT[64][36];
  __shared__ float wT[128][36];
  __shared__ float oL[64][136];
  const int bt0 = blockIdx.x * 64;
  const int b   = bt0 >> 10;
  const int t0  = bt0 & 1023;
  const int t = threadIdx.x;
  const int c4 = (t & 31) * 4;
  const int rowg = t >> 5;
  float acc[8][4];
#pragma unroll
  for (int r = 0; r < 8; ++r)
#pragma unroll
    for (int j = 0; j < 4; ++j) acc[r][j] = 0.f;

  for (int kc = 0; kc < 16; ++kc) {
    {
      const int r = t >> 2, q = t & 3;
      const int c0 = kc * 32 + q * 8;
      const f16x8 v = *(const f16x8*)(ws_h2 + (size_t)(t0 + r + 1) * 32768 +
                                      (size_t)(c0 >> 4) * 1024 + b * 32 + (c0 & 15) * 2);
#pragma unroll
      for (int j = 0; j < 8; ++j) hT[r][q * 8 + j] = (float)v[j];
    }
#pragma unroll
    for (int u = t; u < 1024; u += 256) {
      const int cc = u >> 3, k4 = u & 7;
      *(float4*)&wT[cc][k4 * 4] = *(const float4*)(fcW + (size_t)cc * 512 + kc * 32 + k4 * 4);
    }
    __syncthreads();
#pragma unroll
    for (int k4 = 0; k4 < 8; ++k4) {
      float4 w0 = *(float4*)&wT[c4 + 0][k4 * 4];
      float4 w1 = *(float4*)&wT[c4 + 1][k4 * 4];
      float4 w2 = *(float4*)&wT[c4 + 2][k4 * 4];
      float4 w3 = *(float4*)&wT[c4 + 3][k4 * 4];
#pragma unroll
      for (int rr = 0; rr < 8; ++rr) {
        float4 h = *(float4*)&hT[rowg * 8 + rr][k4 * 4];
        acc[rr][0] += h.x * w0.x + h.y * w0.y + h.z * w0.z + h.w * w0.w;
        acc[rr][1] += h.x * w1.x + h.y * w1.y + h.z * w1.z + h.w * w1.w;
        acc[rr][2] += h.x * w2.x + h.y * w2.y + h.z * w2.z + h.w * w2.w;
        acc[rr][3] += h.x * w3.x + h.y * w3.y + h.z * w3.z + h.w * w3.w;
      }
    }
    __syncthreads();
  }
#pragma unroll
  for (int rr = 0; rr < 8; ++rr)
#pragma unroll
    for (int j = 0; j < 4; ++j)
      oL[rowg * 8 + rr][c4 + j] = acc[rr][j] + fcb[c4 + j];
  __syncthreads();
  float a2[8][4];
#pragma unroll
  for (int r = 0; r < 8; ++r)
#pragma unroll
    for (int j = 0; j < 4; ++j) a2[r][j] = 0.f;
#pragma unroll
  for (int k4 = 0; k4 < 32; ++k4) {
    float4 w0 = *(const float4*)(fc2W + (size_t)(c4 + 0) * 128 + k4 * 4);
    float4 w1 = *(const float4*)(fc2W + (size_t)(c4 + 1) * 128 + k4 * 4);
    float4 w2 = *(const float4*)(fc2W + (size_t)(c4 + 2) * 128 + k4 * 4);
    float4 w3 = *(const float4*)(fc2W + (size_t)(c4 + 3) * 128 + k4 * 4);
#pragma unroll
    for (int rr = 0; rr < 8; ++rr) {
      float4 h = *(float4*)&oL[rowg * 8 + rr][k4 * 4];
      a2[rr][0] += h.x * w0.x + h.y * w0.y + h.z * w0.z + h.w * w0.w;
      a2[rr][1] += h.x * w1.x + h.y * w1.y + h.z * w1.z + h.w * w1.w;
      a2[rr][2] += h.x * w2.x + h.y * w2.y + h.z * w2.z + h.w * w2.w;
      a2[rr][3] += h.x * w3.x + h.y * w3.y + h.z * w3.z + h.w * w3.w;
    }
  }
#pragma unroll
  for (int rr = 0; rr < 8; ++rr) {
    const int r = bt0 + rowg * 8 + rr;
#pragma unroll
    for (int j = 0; j < 4; ++j)
      out[(size_t)r * 128 + c4 + j] = a2[rr][j] + fc2b[c4 + j];
  }
}

extern "C" void kernel_launch(void* const* d_in, const int* in_sizes, int n_in,
                              void* d_out, int out_size, void* d_ws, size_t ws_size,
                              hipStream_t stream) {
  (void)in_sizes; (void)n_in; (void)out_size; (void)ws_size;
  const float* x    = (const float*)d_in[0];
  const float* Wih0 = (const float*)d_in[1];
  const float* Whh0 = (const float*)d_in[2];
  const float* bih0 = (const float*)d_in[3];
  const float* bhh0 = (const float*)d_in[4];
  const float* Wih1 = (const float*)d_in[5];
  const float* Whh1 = (const float*)d_in[6];
  const float* bih1 = (const float*)d_in[7];
  const float* bhh1 = (const float*)d_in[8];
  const float* fcW  = (const float*)d_in[9];
  const float* fcb  = (const float*)d_in[10];
  const float* fc2W = (const float*)d_in[11];
  const float* fc2b = (const float*)d_in[12];

  char* ws = (char*)d_ws;
  f16* xT = (f16*)(ws + OFF_XT);
  float* out = (float*)d_out;

  // per-call init: zero slot-0 of both exchange arrays (h[-1] = 0; slot 0 never verified)
  (void)hipMemsetAsync(ws + OFF_H1S, 0, 32768, stream);
  (void)hipMemsetAsync(ws + OFF_H2S, 0, 32768, stream);

  prep_xT<<<4096, 256, 0, stream>>>(x, xT);
  lstm_persist<<<NWG, THR, 0, stream>>>(Wih0, Whh0, bih0, bhh0,
                                        Wih1, Whh1, bih1, bhh1, ws);
  fc_fused<<<512, 256, 0, stream>>>(ws + OFF_H2S, fcW, fcb, fc2W, fc2b, out);
}

// Round 13
// 3321.429 us; speedup vs baseline: 2.4272x; 2.4272x over previous
//
#include <hip/hip_runtime.h>
#include <math.h>

typedef _Float16 f16;
typedef _Float16 f16x8 __attribute__((ext_vector_type(8)));
typedef _Float16 f16x4 __attribute__((ext_vector_type(4)));
typedef _Float16 f16x2 __attribute__((ext_vector_type(2)));
typedef float f32x16 __attribute__((ext_vector_type(16)));
typedef int i32x4 __attribute__((ext_vector_type(4)));

#define B_ 32
#define T_ 1024
#define I_ 128
#define H_ 512

#define NWG 64          // 32 L0-WGs + 32 L1-WGs (one-way pipeline, R11)
#define THR 512

// ---- workspace layout (bytes) — R11-identical ----
#define OFF_FLAGS 0UL                 // flags0: 32 x 64B; flags1 at +2048; total 4096
#define OFF_H1S   4096UL              // [1025][32768] slot k = h1[t=k-1]; [wg][32b x 16c f16]
#define OFF_H2S   33591296UL          // [1025][32768] slot k = h2[t=k-1]
#define OFF_XT    67178496UL          // f16 [1024][32][128] = 8,388,608
// total 75,567,104 B

__device__ inline f32x16 mfma32(f16x8 a, f16x8 b, f32x16 c) {
  return __builtin_amdgcn_mfma_f32_32x32x16_f16(a, b, c, 0, 0, 0);
}
__device__ inline float fast_sig(float x) { return 1.f / (1.f + __expf(-x)); }
__device__ inline float fast_tanh(float x) {
  float e = __expf(-2.f * fabsf(x));
  float t = (1.f - e) / (1.f + e);
  return x < 0.f ? -t : t;
}

// sc1 = device-coherent (MALL) protocol primitives — R2/R6-proven
__device__ inline unsigned ld_sc1_u32(const unsigned* p) {
  unsigned r;
  asm volatile("global_load_dword %0, %1, off sc1\n\ts_waitcnt vmcnt(0)"
               : "=v"(r) : "v"(p) : "memory");
  return r;
}
__device__ inline void st_sc1_u32(unsigned* p, unsigned v) {
  asm volatile("global_store_dword %0, %1, off sc1" :: "v"(p), "v"(v) : "memory");
}

// LDS XOR-swizzle (R2/R6/R10-proven)
__device__ inline int swz_h(int b, int kbyte) { return b * 1024 + (kbyte ^ ((b & 7) << 4)); }
__device__ inline int swz_x(int b, int kbyte) { return b * 256  + (kbyte ^ ((b & 7) << 4)); }

// x[b][t][i] f32 -> xT[t][b][i] f16
__global__ __launch_bounds__(256) void prep_xT(const float* __restrict__ x, f16* __restrict__ xT) {
  const int idx = blockIdx.x * 256 + threadIdx.x;
  const int n4 = B_ * T_ * I_ / 4;
  if (idx < n4) {
    const int i4 = idx * 4;
    const int i  = i4 & (I_ - 1);
    const int tt = (i4 >> 7) & (T_ - 1);
    const int b  = i4 >> 17;
    float4 v = *(const float4*)(x + i4);
    f16x4 o;
    o[0] = (f16)v.x; o[1] = (f16)v.y; o[2] = (f16)v.z; o[3] = (f16)v.w;
    *(f16x4*)(xT + ((size_t)tt * B_ + b) * I_ + i) = o;
  }
}

// Role-split persistent 2-layer LSTM (R11). L1's step reordered: the h1 gather/stage
// (flags0-gated, but L0 runs ahead so it's non-blocking) happens BEFORE the flags1
// poll, hiding L1's detect latency under useful work. All else R11-verbatim.
__global__ __launch_bounds__(THR, 1) void lstm_persist(
    const float* __restrict__ Wih0, const float* __restrict__ Whh0,
    const float* __restrict__ bih0, const float* __restrict__ bhh0,
    const float* __restrict__ Wih1, const float* __restrict__ Whh1,
    const float* __restrict__ bih1, const float* __restrict__ bhh1,
    char* ws) {
  __shared__ i32x4 h1l4[2048];          // 32KB  h1 tile (swizzled)
  __shared__ i32x4 h2l4[2048];          // 32KB  h2 tile (L1 role)
  __shared__ i32x4 xl4[512];            // 8KB   x tile (L0 role)
  __shared__ float gbuf[2 * 32 * 68];   // gate partials [kq][32b][64c pad 68]
  __shared__ float biasl[64];

  const int tid  = threadIdx.x;
  const int wgid = blockIdx.x;
  const int role = wgid >> 5;           // 0 = L0, 1 = L1
  const int gid  = wgid & 31;
  const int lane = tid & 63;
  const int wv   = tid >> 6;
  const int nt   = wv & 1;              // 32-col N-tile (MFMA waves 0-3)
  const int kq   = (wv >> 1) & 1;       // K-half
  const int bl   = lane & 31;
  const int kg   = lane >> 5;

  unsigned* flags0 = (unsigned*)(ws + OFF_FLAGS);
  unsigned* flags1 = (unsigned*)(ws + OFF_FLAGS + 2048);
  const char* h1base = ws + OFF_H1S;
  const char* h2base = ws + OFF_H2S;

  if (tid < 64) {
    const int g = tid >> 4, hc = tid & 15;
    const int row = g * 512 + gid * 16 + hc;
    biasl[tid] = role ? (bih1[row] + bhh1[row]) : (bih0[row] + bhh0[row]);
  }

  // ---- weight preload into VGPRs (R10/R11-identical fragments; MFMA waves only) ----
  const int n    = nt * 32 + bl;
  const int wrow = (n >> 4) * 512 + gid * 16 + (n & 15);
  f16x8 wreg[32];
  if (role == 0) {
    if (wv < 4) {
#pragma unroll
      for (int ks = 0; ks < 20; ++ks) {
        const int k = kq * 320 + ks * 16 + kg * 8;
        const float* src = (k < I_) ? (Wih0 + (size_t)wrow * I_ + k)
                                    : (Whh0 + (size_t)wrow * H_ + (k - I_));
        float4 v0 = *(const float4*)(src);
        float4 v1 = *(const float4*)(src + 4);
        f16x8 h;
        h[0] = (f16)v0.x; h[1] = (f16)v0.y; h[2] = (f16)v0.z; h[3] = (f16)v0.w;
        h[4] = (f16)v1.x; h[5] = (f16)v1.y; h[6] = (f16)v1.z; h[7] = (f16)v1.w;
        wreg[ks] = h;
      }
    }
  } else {
    if (wv < 4) {
#pragma unroll
      for (int ks = 0; ks < 32; ++ks) {
        const int k = kq * 512 + ks * 16 + kg * 8;
        const float* src = (k < H_) ? (Wih1 + (size_t)wrow * H_ + k)
                                    : (Whh1 + (size_t)wrow * H_ + (k - H_));
        float4 v0 = *(const float4*)(src);
        float4 v1 = *(const float4*)(src + 4);
        f16x8 h;
        h[0] = (f16)v0.x; h[1] = (f16)v0.y; h[2] = (f16)v0.z; h[3] = (f16)v0.w;
        h[4] = (f16)v1.x; h[5] = (f16)v1.y; h[6] = (f16)v1.z; h[7] = (f16)v1.w;
        wreg[ks] = h;
      }
    }
  }

  float cst0 = 0.f, cst1 = 0.f;         // cell state for pointwise threads (tid<256)
  const char* h1c = (const char*)h1l4;
  const char* h2c = (const char*)h2l4;
  const char* xc  = (const char*)xl4;

  __syncthreads();

  if (role == 0) {
    // ================= layer 0 — the critical h1 loop (R11-verbatim) =================
    for (int s = 0; s < T_; ++s) {
      i32x4 xv = ((const i32x4*)(ws + OFF_XT))[(size_t)s * 512 + tid];  // prefetch

      if (s >= 1) {                      // gate: all flags0 >= s (h1[s-1] in slot s)
        if (tid < 64) {
          const unsigned tgt = (unsigned)s;
          const unsigned* fp = flags0 + (tid < 32 ? tid : 0) * 16;
          const bool active = tid < 32;
          for (;;) {
            unsigned v = ld_sc1_u32(fp);
            if (!active) v = tgt;
            if (__all((int)(v >= tgt))) break;
            __builtin_amdgcn_s_sleep(1);
          }
        }
        __syncthreads();
      }

      // stage h1[s-1] (slot s) + x[s] -> swizzled LDS
      {
        const i32x4* src = (const i32x4*)(h1base + (size_t)s * 32768);
#pragma unroll
        for (int r = 0; r < 4; ++r) {
          const int u = r * 512 + tid;
          i32x4 v = src[u];
          const int wgs = u >> 6, b = (u >> 1) & 31, half = u & 1;
          *(i32x4*)((char*)h1l4 + swz_h(b, wgs * 32 + half * 16)) = v;
        }
      }
      *(i32x4*)((char*)xl4 + swz_x(tid >> 4, (tid & 15) * 16)) = xv;
      __syncthreads();

      // MFMA (waves 0-3)
      if (wv < 4) {
        f32x16 acc = {};
        if (kq == 0) {
#pragma unroll
          for (int ks = 0; ks < 8; ++ks) {
            f16x8 a = *(const f16x8*)(xc + swz_x(bl, (ks * 16 + kg * 8) * 2));
            acc = mfma32(a, wreg[ks], acc);
          }
#pragma unroll
          for (int ks = 8; ks < 20; ++ks) {
            f16x8 a = *(const f16x8*)(h1c + swz_h(bl, (ks * 16 + kg * 8 - I_) * 2));
            acc = mfma32(a, wreg[ks], acc);
          }
        } else {
#pragma unroll
          for (int ks = 0; ks < 20; ++ks) {
            f16x8 a = *(const f16x8*)(h1c + swz_h(bl, (192 + ks * 16 + kg * 8) * 2));
            acc = mfma32(a, wreg[ks], acc);
          }
        }
        const int cb = nt * 32 + bl;
#pragma unroll
        for (int r = 0; r < 16; ++r) {
          const int row = (r & 3) + 8 * (r >> 2) + 4 * kg;   // m74-verified C/D layout
          gbuf[kq * 2176 + row * 68 + cb] = acc[r];
        }
      }
      __syncthreads();

      // pointwise + block-contiguous sc1 store
      if (tid < 256) {
        const int rb = tid >> 3, hp = tid & 7;
        const float* gr = gbuf + rb * 68;
        float hv[2];
#pragma unroll
        for (int cc = 0; cc < 2; ++cc) {
          const int c = 2 * hp + cc;
          const float pi = gr[c]      + gr[2176 + c]      + biasl[c];
          const float pf = gr[16 + c] + gr[2176 + 16 + c] + biasl[16 + c];
          const float pg = gr[32 + c] + gr[2176 + 32 + c] + biasl[32 + c];
          const float po = gr[48 + c] + gr[2176 + 48 + c] + biasl[48 + c];
          const float ig = fast_sig(pi), fg = fast_sig(pf);
          const float gg = fast_tanh(pg), og = fast_sig(po);
          const float cprev = cc ? cst1 : cst0;
          const float cnew = fg * cprev + ig * gg;
          if (cc) cst1 = cnew; else cst0 = cnew;
          hv[cc] = og * fast_tanh(cnew);
        }
        f16x2 pk; pk[0] = (f16)hv[0]; pk[1] = (f16)hv[1];
        unsigned* dst = (unsigned*)(h1base + (size_t)(s + 1) * 32768 +
                                    (size_t)gid * 1024 + rb * 32 + hp * 4);
        st_sc1_u32(dst, __builtin_bit_cast(unsigned, pk));
      }

      asm volatile("s_waitcnt vmcnt(0)" ::: "memory");
      __syncthreads();
      if (tid == 0) st_sc1_u32(flags0 + gid * 16, (unsigned)(s + 1));
      __builtin_amdgcn_sched_barrier(0);
    }
  } else {
    // ================= layer 1 — self-paced; h1 work hoisted before flags1 poll =================
    for (int t = 0; t < T_; ++t) {
      // A: gate on flags0 >= t+1 (h1[t] in slot t+1) — L0 runs ahead, normally instant
      if (tid < 64) {
        const unsigned tgt = (unsigned)(t + 1);
        const unsigned* fp = flags0 + (tid < 32 ? tid : 0) * 16;
        const bool active = tid < 32;
        for (;;) {
          unsigned v = ld_sc1_u32(fp);
          if (!active) v = tgt;
          if (__all((int)(v >= tgt))) break;
          __builtin_amdgcn_s_sleep(1);
        }
      }
      __syncthreads();

      // B/C: gather + stage h1[t] (slot t+1) — useful work while peers' flags1 propagate
      {
        const i32x4* src = (const i32x4*)(h1base + (size_t)(t + 1) * 32768);
#pragma unroll
        for (int r = 0; r < 4; ++r) {
          const int u = r * 512 + tid;
          i32x4 v = src[u];
          const int wgs = u >> 6, b = (u >> 1) & 31, half = u & 1;
          *(i32x4*)((char*)h1l4 + swz_h(b, wgs * 32 + half * 16)) = v;
        }
      }

      // D: gate on flags1 >= t (h2[t-1] in slot t) — detect latency hidden by B/C
      if (t >= 1) {
        if (tid < 64) {
          const unsigned tgt = (unsigned)t;
          const unsigned* fp = flags1 + (tid < 32 ? tid : 0) * 16;
          const bool active = tid < 32;
          for (;;) {
            unsigned v = ld_sc1_u32(fp);
            if (!active) v = tgt;
            if (__all((int)(v >= tgt))) break;
            __builtin_amdgcn_s_sleep(1);
          }
        }
      }
      __syncthreads();

      // E: gather + stage h2[t-1] (slot t)
      {
        const i32x4* src = (const i32x4*)(h2base + (size_t)t * 32768);
#pragma unroll
        for (int r = 0; r < 4; ++r) {
          const int u = r * 512 + tid;
          i32x4 v = src[u];
          const int wgs = u >> 6, b = (u >> 1) & 31, half = u & 1;
          *(i32x4*)((char*)h2l4 + swz_h(b, wgs * 32 + half * 16)) = v;
        }
      }
      __syncthreads();

      // MFMA (waves 0-3; R11 L1 body verbatim)
      if (wv < 4) {
        f32x16 acc = {};
        if (kq == 0) {
#pragma unroll
          for (int ks = 0; ks < 32; ++ks) {
            f16x8 a = *(const f16x8*)(h1c + swz_h(bl, (ks * 16 + kg * 8) * 2));
            acc = mfma32(a, wreg[ks], acc);
          }
        } else {
#pragma unroll
          for (int ks = 0; ks < 32; ++ks) {
            f16x8 a = *(const f16x8*)(h2c + swz_h(bl, (ks * 16 + kg * 8) * 2));
            acc = mfma32(a, wreg[ks], acc);
          }
        }
        const int cb = nt * 32 + bl;
#pragma unroll
        for (int r = 0; r < 16; ++r) {
          const int row = (r & 3) + 8 * (r >> 2) + 4 * kg;
          gbuf[kq * 2176 + row * 68 + cb] = acc[r];
        }
      }
      __syncthreads();

      // pointwise + h2 store (R11 verbatim)
      if (tid < 256) {
        const int rb = tid >> 3, hp = tid & 7;
        const float* gr = gbuf + rb * 68;
        float hv[2];
#pragma unroll
        for (int cc = 0; cc < 2; ++cc) {
          const int c = 2 * hp + cc;
          const float pi = gr[c]      + gr[2176 + c]      + biasl[c];
          const float pf = gr[16 + c] + gr[2176 + 16 + c] + biasl[16 + c];
          const float pg = gr[32 + c] + gr[2176 + 32 + c] + biasl[32 + c];
          const float po = gr[48 + c] + gr[2176 + 48 + c] + biasl[48 + c];
          const float ig = fast_sig(pi), fg = fast_sig(pf);
          const float gg = fast_tanh(pg), og = fast_sig(po);
          const float cprev = cc ? cst1 : cst0;
          const float cnew = fg * cprev + ig * gg;
          if (cc) cst1 = cnew; else cst0 = cnew;
          hv[cc] = og * fast_tanh(cnew);
        }
        f16x2 pk; pk[0] = (f16)hv[0]; pk[1] = (f16)hv[1];
        unsigned* dst = (unsigned*)(h2base + (size_t)(t + 1) * 32768 +
                                    (size_t)gid * 1024 + rb * 32 + hp * 4);
        st_sc1_u32(dst, __builtin_bit_cast(unsigned, pk));
      }

      asm volatile("s_waitcnt vmcnt(0)" ::: "memory");
      __syncthreads();
      if (tid == 0) st_sc1_u32(flags1 + gid * 16, (unsigned)(t + 1));
      __builtin_amdgcn_sched_barrier(0);
    }
  }
}

// fused FC1+FC2 reading block layout (R6-identical): rows bt = b*1024 + t.
__global__ __launch_bounds__(256) void fc_fused(const char* __restrict__ ws_h2,
                                                const float* __restrict__ fcW,
                                                const float* __restrict__ fcb,
                                                const float* __restrict__ fc2W,
                                                const float* __restrict__ fc2b,
                                                float* __restrict__ out) {
  __shared__ float hT[64][36];
  __shared__ float wT[128][36];
  __shared__ float oL[64][136];
  const int bt0 = blockIdx.x * 64;
  const int b   = bt0 >> 10;
  const int t0  = bt0 & 1023;
  const int t = threadIdx.x;
  const int c4 = (t & 31) * 4;
  const int rowg = t >> 5;
  float acc[8][4];
#pragma unroll
  for (int r = 0; r < 8; ++r)
#pragma unroll
    for (int j = 0; j < 4; ++j) acc[r][j] = 0.f;

  for (int kc = 0; kc < 16; ++kc) {
    {
      const int r = t >> 2, q = t & 3;
      const int c0 = kc * 32 + q * 8;
      const f16x8 v = *(const f16x8*)(ws_h2 + (size_t)(t0 + r + 1) * 32768 +
                                      (size_t)(c0 >> 4) * 1024 + b * 32 + (c0 & 15) * 2);
#pragma unroll
      for (int j = 0; j < 8; ++j) hT[r][q * 8 + j] = (float)v[j];
    }
#pragma unroll
    for (int u = t; u < 1024; u += 256) {
      const int cc = u >> 3, k4 = u & 7;
      *(float4*)&wT[cc][k4 * 4] = *(const float4*)(fcW + (size_t)cc * 512 + kc * 32 + k4 * 4);
    }
    __syncthreads();
#pragma unroll
    for (int k4 = 0; k4 < 8; ++k4) {
      float4 w0 = *(float4*)&wT[c4 + 0][k4 * 4];
      float4 w1 = *(float4*)&wT[c4 + 1][k4 * 4];
      float4 w2 = *(float4*)&wT[c4 + 2][k4 * 4];
      float4 w3 = *(float4*)&wT[c4 + 3][k4 * 4];
#pragma unroll
      for (int rr = 0; rr < 8; ++rr) {
        float4 h = *(float4*)&hT[rowg * 8 + rr][k4 * 4];
        acc[rr][0] += h.x * w0.x + h.y * w0.y + h.z * w0.z + h.w * w0.w;
        acc[rr][1] += h.x * w1.x + h.y * w1.y + h.z * w1.z + h.w * w1.w;
        acc[rr][2] += h.x * w2.x + h.y * w2.y + h.z * w2.z + h.w * w2.w;
        acc[rr][3] += h.x * w3.x + h.y * w3.y + h.z * w3.z + h.w * w3.w;
      }
    }
    __syncthreads();
  }
#pragma unroll
  for (int rr = 0; rr < 8; ++rr)
#pragma unroll
    for (int j = 0; j < 4; ++j)
      oL[rowg * 8 + rr][c4 + j] = acc[rr][j] + fcb[c4 + j];
  __syncthreads();
  float a2[8][4];
#pragma unroll
  for (int r = 0; r < 8; ++r)
#pragma unroll
    for (int j = 0; j < 4; ++j) a2[r][j] = 0.f;
#pragma unroll
  for (int k4 = 0; k4 < 32; ++k4) {
    float4 w0 = *(const float4*)(fc2W + (size_t)(c4 + 0) * 128 + k4 * 4);
    float4 w1 = *(const float4*)(fc2W + (size_t)(c4 + 1) * 128 + k4 * 4);
    float4 w2 = *(const float4*)(fc2W + (size_t)(c4 + 2) * 128 + k4 * 4);
    float4 w3 = *(const float4*)(fc2W + (size_t)(c4 + 3) * 128 + k4 * 4);
#pragma unroll
    for (int rr = 0; rr < 8; ++rr) {
      float4 h = *(float4*)&oL[rowg * 8 + rr][k4 * 4];
      a2[rr][0] += h.x * w0.x + h.y * w0.y + h.z * w0.z + h.w * w0.w;
      a2[rr][1] += h.x * w1.x + h.y * w1.y + h.z * w1.z + h.w * w1.w;
      a2[rr][2] += h.x * w2.x + h.y * w2.y + h.z * w2.z + h.w * w2.w;
      a2[rr][3] += h.x * w3.x + h.y * w3.y + h.z * w3.z + h.w * w3.w;
    }
  }
#pragma unroll
  for (int rr = 0; rr < 8; ++rr) {
    const int r = bt0 + rowg * 8 + rr;
#pragma unroll
    for (int j = 0; j < 4; ++j)
      out[(size_t)r * 128 + c4 + j] = a2[rr][j] + fc2b[c4 + j];
  }
}

extern "C" void kernel_launch(void* const* d_in, const int* in_sizes, int n_in,
                              void* d_out, int out_size, void* d_ws, size_t ws_size,
                              hipStream_t stream) {
  (void)in_sizes; (void)n_in; (void)out_size; (void)ws_size;
  const float* x    = (const float*)d_in[0];
  const float* Wih0 = (const float*)d_in[1];
  const float* Whh0 = (const float*)d_in[2];
  const float* bih0 = (const float*)d_in[3];
  const float* bhh0 = (const float*)d_in[4];
  const float* Wih1 = (const float*)d_in[5];
  const float* Whh1 = (const float*)d_in[6];
  const float* bih1 = (const float*)d_in[7];
  const float* bhh1 = (const float*)d_in[8];
  const float* fcW  = (const float*)d_in[9];
  const float* fcb  = (const float*)d_in[10];
  const float* fc2W = (const float*)d_in[11];
  const float* fc2b = (const float*)d_in[12];

  char* ws = (char*)d_ws;
  f16* xT = (f16*)(ws + OFF_XT);
  float* out = (float*)d_out;

  // per-call init: both flag arrays + zero slot-0 of both exchange arrays (h[-1] = 0)
  (void)hipMemsetAsync(ws + OFF_FLAGS, 0, 4096, stream);
  (void)hipMemsetAsync(ws + OFF_H1S, 0, 32768, stream);
  (void)hipMemsetAsync(ws + OFF_H2S, 0, 32768, stream);

  prep_xT<<<4096, 256, 0, stream>>>(x, xT);
  lstm_persist<<<NWG, THR, 0, stream>>>(Wih0, Whh0, bih0, bhh0,
                                        Wih1, Whh1, bih1, bhh1, ws);
  fc_fused<<<512, 256, 0, stream>>>(ws + OFF_H2S, fcW, fcb, fc2W, fc2b, out);
}